// Round 1
// baseline (468.681 us; speedup 1.0000x reference)
//
#include <hip/hip_runtime.h>

#define TOK 64
#define DIMS 256
#define NHEAD 8
#define HDIM 32

typedef __attribute__((ext_vector_type(8))) short short8;
typedef __attribute__((ext_vector_type(4))) float floatx4;
typedef __attribute__((ext_vector_type(2))) unsigned int uintx2;

__device__ __forceinline__ unsigned short f2bf(float f) {
  unsigned int u = __float_as_uint(f);
  u += 0x7fffu + ((u >> 16) & 1u);   // round-to-nearest-even
  return (unsigned short)(u >> 16);
}

// ---- prep: W->bf16 (scale folded into Wq/bq), rel_bias gather transposed [h][j][i]
__global__ void prep_w(const float* __restrict__ wq, const float* __restrict__ bq,
                       const float* __restrict__ wk, const float* __restrict__ bk,
                       const float* __restrict__ wv, const float* __restrict__ bv,
                       const float* __restrict__ bias_table, const int* __restrict__ rel_index,
                       unsigned short* __restrict__ Wqkv, float* __restrict__ bias,
                       float* __restrict__ rbT) {
  const int o = blockIdx.x;      // 0..767  (output feature row of [768][256])
  const int t = threadIdx.x;     // 0..255
  const float scale = 0.17677669529663687f;  // 1/sqrt(32)
  const float* src; float s;
  if (o < 256)      { src = wq + o * 256;         s = scale; }
  else if (o < 512) { src = wk + (o - 256) * 256; s = 1.0f; }
  else              { src = wv + (o - 512) * 256; s = 1.0f; }
  Wqkv[o * 256 + t] = f2bf(src[t] * s);
  if (o == 0)      bias[t]       = bq[t] * scale;
  else if (o == 1) bias[256 + t] = bk[t];
  else if (o == 2) bias[512 + t] = bv[t];
  if (o < 128) {
    int idx = o * 256 + t;            // = h*4096 + j*64 + i
    int h = idx >> 12, j = (idx >> 6) & 63, i = idx & 63;
    rbT[idx] = bias_table[rel_index[i * 64 + j] * 8 + h];
  }
}

// ---- prep: transpose mask to [w][j][i] so epilogue loads are float4
__global__ void prep_mask(const float* __restrict__ mask, float* __restrict__ maskT) {
  int idx = blockIdx.x * 256 + threadIdx.x;  // = w*4096 + j*64 + i
  int w = idx >> 12, j = (idx >> 6) & 63, i = idx & 63;
  maskT[idx] = mask[(w << 12) + (i << 6) + j];
}

// ---- fused QKV projection + windowed attention. One block per window.
__global__ __launch_bounds__(256, 1)
void attn_fused(const float* __restrict__ hidden, const unsigned short* __restrict__ Wqkv,
                const float* __restrict__ bias, const float* __restrict__ rbT,
                const float* __restrict__ maskT, float* __restrict__ out) {
  // phase1: A bf16 [64][264]; phase2: per-wave P [64][72]
  __shared__ unsigned short sAP[18432];
  __shared__ unsigned short sQ[18432];   // [8 heads][64 tok][36]  (32 + 4 pad)
  __shared__ unsigned short sK[18432];   // same
  __shared__ unsigned short sV[18432];   // transposed: [8 heads][32 d][72]  (64 + 8 pad)

  const int b    = blockIdx.x;
  const int t    = threadIdx.x;
  const int wave = t >> 6;
  const int lane = t & 63;
  const int quad = lane >> 4;
  const int l16  = lane & 15;

  // ---------- stage hidden -> sAP (bf16, row stride 264)
  {
    const float* hsrc = hidden + (size_t)b * (TOK * DIMS);
    #pragma unroll
    for (int it = 0; it < 16; ++it) {
      int e = (it * 256 + t) * 4;
      int row = e >> 8, col = e & 255;
      floatx4 v = *(const floatx4*)(hsrc + e);
      union { unsigned short s[4]; uintx2 u; } pk;
      pk.s[0] = f2bf(v.x); pk.s[1] = f2bf(v.y);
      pk.s[2] = f2bf(v.z); pk.s[3] = f2bf(v.w);
      *(uintx2*)&sAP[row * 264 + col] = pk.u;
    }
  }
  __syncthreads();

  // ---------- QKV GEMM: [64 x 768] = A x W^T (+bias), scattered into sQ/sK/sV
  {
    const int colw = wave * 192;
    #pragma unroll 1
    for (int pass = 0; pass < 2; ++pass) {
      const int pbase = colw + pass * 96;
      floatx4 acc[6][4];
      #pragma unroll
      for (int nt = 0; nt < 6; ++nt)
        #pragma unroll
        for (int mt = 0; mt < 4; ++mt)
          acc[nt][mt] = (floatx4){0.f, 0.f, 0.f, 0.f};
      #pragma unroll
      for (int kk = 0; kk < 8; ++kk) {
        const int koff = kk * 32 + quad * 8;
        short8 af[4];
        #pragma unroll
        for (int mt = 0; mt < 4; ++mt)
          af[mt] = *(const short8*)&sAP[(mt * 16 + l16) * 264 + koff];
        #pragma unroll
        for (int nt = 0; nt < 6; ++nt) {
          const short8 wf = *(const short8*)(Wqkv + (pbase + nt * 16 + l16) * 256 + koff);
          #pragma unroll
          for (int mt = 0; mt < 4; ++mt)
            acc[nt][mt] = __builtin_amdgcn_mfma_f32_16x16x32_bf16(af[mt], wf, acc[nt][mt], 0, 0, 0);
        }
      }
      // epilogue: +bias, cvt bf16, scatter
      #pragma unroll
      for (int nt = 0; nt < 6; ++nt) {
        const int col = pbase + nt * 16 + l16;
        const float bo = bias[col];
        const int region = col >> 8;        // 0=Q 1=K 2=V (uniform per tile)
        const int head = (col >> 5) & 7;
        const int c = col & 31;
        #pragma unroll
        for (int mt = 0; mt < 4; ++mt) {
          const int row0 = mt * 16 + quad * 4;
          if (region == 2) {
            union { unsigned short s[4]; uintx2 u; } pk;
            #pragma unroll
            for (int r = 0; r < 4; ++r) pk.s[r] = f2bf(acc[nt][mt][r] + bo);
            *(uintx2*)&sV[(head * 32 + c) * 72 + row0] = pk.u;   // transposed store
          } else {
            unsigned short* dst = (region == 0 ? sQ : sK) + (head * 64 + row0) * 36 + c;
            #pragma unroll
            for (int r = 0; r < 4; ++r) dst[r * 36] = f2bf(acc[nt][mt][r] + bo);
          }
        }
      }
    }
  }
  __syncthreads();

  // ---------- attention: wave handles heads 2*wave, 2*wave+1
  const int wmod = b & 63;
  const float* mw = maskT + wmod * 4096;
  unsigned short* sP = sAP + wave * (64 * 72);

  #pragma unroll 1
  for (int rep = 0; rep < 2; ++rep) {
    const int h = wave * 2 + rep;
    // S = Q_h K_h^T (scale already folded into Q)
    floatx4 sacc[4][4];
    #pragma unroll
    for (int mt = 0; mt < 4; ++mt)
      #pragma unroll
      for (int nt = 0; nt < 4; ++nt)
        sacc[mt][nt] = (floatx4){0.f, 0.f, 0.f, 0.f};
    short8 qf[4];
    #pragma unroll
    for (int mt = 0; mt < 4; ++mt) {
      const unsigned short* qp = sQ + (h * 64 + mt * 16 + l16) * 36 + quad * 8;
      union { short8 s8; uintx2 u2[2]; } u;
      u.u2[0] = *(const uintx2*)qp;
      u.u2[1] = *(const uintx2*)(qp + 4);
      qf[mt] = u.s8;
    }
    #pragma unroll
    for (int nt = 0; nt < 4; ++nt) {
      const unsigned short* kp = sK + (h * 64 + nt * 16 + l16) * 36 + quad * 8;
      union { short8 s8; uintx2 u2[2]; } u;
      u.u2[0] = *(const uintx2*)kp;
      u.u2[1] = *(const uintx2*)(kp + 4);
      const short8 kf = u.s8;
      #pragma unroll
      for (int mt = 0; mt < 4; ++mt)
        sacc[mt][nt] = __builtin_amdgcn_mfma_f32_16x16x32_bf16(qf[mt], kf, sacc[mt][nt], 0, 0, 0);
    }
    // + rel_bias + mask (both stored [.][j][i] -> float4 over the 4 C-regs)
    const float* rb = rbT + h * 4096;
    #pragma unroll
    for (int mt = 0; mt < 4; ++mt) {
      const int i0 = mt * 16 + quad * 4;
      #pragma unroll
      for (int nt = 0; nt < 4; ++nt) {
        const int j = nt * 16 + l16;
        floatx4 rv = *(const floatx4*)(rb + j * 64 + i0);
        floatx4 mv = *(const floatx4*)(mw + j * 64 + i0);
        sacc[mt][nt] += rv + mv;
      }
    }
    // softmax over j: row r=quad*4+reg lives in the 16 lanes of this quad
    #pragma unroll
    for (int mt = 0; mt < 4; ++mt) {
      #pragma unroll
      for (int r = 0; r < 4; ++r) {
        float v0 = sacc[mt][0][r], v1 = sacc[mt][1][r];
        float v2 = sacc[mt][2][r], v3 = sacc[mt][3][r];
        float mx = fmaxf(fmaxf(v0, v1), fmaxf(v2, v3));
        mx = fmaxf(mx, __shfl_xor(mx, 1));
        mx = fmaxf(mx, __shfl_xor(mx, 2));
        mx = fmaxf(mx, __shfl_xor(mx, 4));
        mx = fmaxf(mx, __shfl_xor(mx, 8));
        float e0 = __expf(v0 - mx), e1 = __expf(v1 - mx);
        float e2 = __expf(v2 - mx), e3 = __expf(v3 - mx);
        float sm = (e0 + e1) + (e2 + e3);
        sm += __shfl_xor(sm, 1);
        sm += __shfl_xor(sm, 2);
        sm += __shfl_xor(sm, 4);
        sm += __shfl_xor(sm, 8);
        const float inv = __builtin_amdgcn_rcpf(sm);
        sacc[mt][0][r] = e0 * inv; sacc[mt][1][r] = e1 * inv;
        sacc[mt][2][r] = e2 * inv; sacc[mt][3][r] = e3 * inv;
      }
    }
    // P -> per-wave LDS [64][72] bf16
    #pragma unroll
    for (int mt = 0; mt < 4; ++mt) {
      const int i0 = mt * 16 + quad * 4;
      #pragma unroll
      for (int nt = 0; nt < 4; ++nt) {
        const int j = nt * 16 + l16;
        #pragma unroll
        for (int r = 0; r < 4; ++r)
          sP[(i0 + r) * 72 + j] = f2bf(sacc[mt][nt][r]);
      }
    }
    __syncthreads();
    // ctx = P x V_h  [64 x 32]
    floatx4 cacc[4][2];
    #pragma unroll
    for (int mt = 0; mt < 4; ++mt) {
      cacc[mt][0] = (floatx4){0.f, 0.f, 0.f, 0.f};
      cacc[mt][1] = (floatx4){0.f, 0.f, 0.f, 0.f};
    }
    #pragma unroll
    for (int kk = 0; kk < 2; ++kk) {
      const int joff = kk * 32 + quad * 8;
      short8 pf[4];
      #pragma unroll
      for (int mt = 0; mt < 4; ++mt)
        pf[mt] = *(const short8*)&sP[(mt * 16 + l16) * 72 + joff];
      #pragma unroll
      for (int dt = 0; dt < 2; ++dt) {
        const short8 vf = *(const short8*)&sV[(h * 32 + dt * 16 + l16) * 72 + joff];
        #pragma unroll
        for (int mt = 0; mt < 4; ++mt)
          cacc[mt][dt] = __builtin_amdgcn_mfma_f32_16x16x32_bf16(pf[mt], vf, cacc[mt][dt], 0, 0, 0);
      }
    }
    // store ctx (fp32)
    float* ob = out + (size_t)b * (TOK * DIMS) + h * 32;
    #pragma unroll
    for (int mt = 0; mt < 4; ++mt) {
      const int i0 = mt * 16 + quad * 4;
      #pragma unroll
      for (int dt = 0; dt < 2; ++dt) {
        #pragma unroll
        for (int r = 0; r < 4; ++r)
          ob[(i0 + r) * 256 + dt * 16 + l16] = cacc[mt][dt][r];
      }
    }
  }
}

extern "C" void kernel_launch(void* const* d_in, const int* in_sizes, int n_in,
                              void* d_out, int out_size, void* d_ws, size_t ws_size,
                              hipStream_t stream) {
  const float* hidden = (const float*)d_in[0];
  const float* mask   = (const float*)d_in[1];
  const float* wq = (const float*)d_in[2];
  const float* bq = (const float*)d_in[3];
  const float* wk = (const float*)d_in[4];
  const float* bk = (const float*)d_in[5];
  const float* wv = (const float*)d_in[6];
  const float* bv = (const float*)d_in[7];
  const float* bias_table = (const float*)d_in[8];
  const int*   rel_index  = (const int*)d_in[9];

  char* ws = (char*)d_ws;
  unsigned short* Wqkv = (unsigned short*)ws;               // 393216 B
  float* bias  = (float*)(ws + 393216);                     //   3072 B
  float* rbT   = (float*)(ws + 393216 + 3072);              // 131072 B
  float* maskT = (float*)(ws + 393216 + 3072 + 131072);     // 1048576 B

  prep_w<<<768, 256, 0, stream>>>(wq, bq, wk, bk, wv, bv, bias_table, rel_index,
                                  Wqkv, bias, rbT);
  prep_mask<<<1024, 256, 0, stream>>>(mask, maskT);
  attn_fused<<<2048, 256, 0, stream>>>(hidden, Wqkv, bias, rbT, maskT, (float*)d_out);
}